// Round 10
// baseline (1730.899 us; speedup 1.0000x reference)
//
#include <hip/hip_runtime.h>
#include <math.h>

#define NQ 4096
#define NC 1024
#define DSP 512
#define AMB 513
#define NITER 20
#define NPART 256
#define NSPLIT 4

typedef __bf16 bf16x8 __attribute__((ext_vector_type(8)));
typedef float f32x4 __attribute__((ext_vector_type(4)));
typedef unsigned short ushort4v __attribute__((ext_vector_type(4)));
typedef unsigned short ushort8v __attribute__((ext_vector_type(8)));

// ---- two-term bf16 split: x ~= hi + lo, error ~2^-18 relative --------------
__device__ __forceinline__ void splitbf(float x, unsigned short& h,
                                        unsigned short& l) {
  unsigned u = __float_as_uint(x);
  unsigned hb = (u + 0x7fffu + ((u >> 16) & 1u)) & 0xffff0000u;
  float fh = __uint_as_float(hb);
  float r = x - fh;
  unsigned ur = __float_as_uint(r);
  h = (unsigned short)(hb >> 16);
  l = (unsigned short)((ur + 0x7fffu + ((ur >> 16) & 1u)) >> 16);
}

// ---------------- setup ------------------------------------------------------
__global__ void k_setup_q(const float* __restrict__ q, float* __restrict__ q0,
                          unsigned short* __restrict__ Qh,
                          unsigned short* __restrict__ Ql,
                          unsigned short* __restrict__ Qth,
                          unsigned short* __restrict__ Qtl) {
  int tid = blockIdx.x * blockDim.x + threadIdx.x;
  int stride = gridDim.x * blockDim.x;
  for (int idx = tid; idx < NQ * DSP; idx += stride) {
    int i = idx >> 9, k = idx & 511;
    float v = q[i * AMB + 1 + k];
    unsigned short h, l;
    splitbf(v, h, l);
    Qh[idx] = h;
    Ql[idx] = l;
    size_t tq = ((size_t)(i >> 4) * DSP + k) * 16 + (i & 15);
    Qth[tq] = h;
    Qtl[tq] = l;
  }
  for (int i = tid; i < NQ; i += stride) q0[i] = q[i * AMB];
}

__global__ void k_setup_p(const float* __restrict__ p, float* __restrict__ p0,
                          float* __restrict__ Ps,
                          unsigned short* __restrict__ Ph,
                          unsigned short* __restrict__ Pl) {
  int tid = blockIdx.x * blockDim.x + threadIdx.x;
  int stride = gridDim.x * blockDim.x;
  for (int idx = tid; idx < NC * DSP; idx += stride) {
    int j = idx >> 9, k = idx & 511;
    float v = p[j * AMB + 1 + k];
    Ps[idx] = v;
    splitbf(v, Ph[idx], Pl[idx]);
  }
  for (int j = tid; j < NC; j += stride) p0[j] = p[j * AMB];
}

// ---------------- GEMM1: 64x128 tile, 48KB LDS -> 2 blocks/CU ---------------
__global__ __launch_bounds__(256) void k_gemm1(
    const unsigned short* __restrict__ Qh, const unsigned short* __restrict__ Ql,
    const unsigned short* __restrict__ Ph, const unsigned short* __restrict__ Pl,
    const float* __restrict__ q0, const float* __restrict__ p0,
    float* __restrict__ S) {
  __shared__ __align__(16) char smem[49152];
  unsigned short* st = (unsigned short*)smem;
  float* sout = (float*)smem;  // 64x130 f32

  int b = blockIdx.x;
  int xcd = b & 7, m = b >> 3;
  int i0 = (xcd * 8 + (m & 7)) * 64;
  int j0 = (m >> 3) * 128;

  int t = threadIdx.x;
  int lane = t & 63;
  int w = t >> 6;
  int wi = (w & 1) * 32, wj = (w >> 1) * 64;
  int m16 = lane & 15;
  int kc8 = lane >> 4;

  const unsigned short* src = (w == 0) ? Qh : (w == 1) ? Ql : (w == 2) ? Ph : Pl;
  int arrOff = (w == 0) ? 0 : (w == 1) ? 2048 : (w == 2) ? 4096 : 8192;
  int lr = lane >> 2;
  int lc = lane & 3;

  f32x4 acc[2][4];
#pragma unroll
  for (int r = 0; r < 2; ++r)
#pragma unroll
    for (int c = 0; c < 4; ++c) acc[r][c] = (f32x4){0.f, 0.f, 0.f, 0.f};

  auto stage_fn = [&](int kc16, int buf) {
    unsigned short* dstb = st + buf * 12288 + arrOff;
    if (w < 2) {
#pragma unroll
      for (int u = 0; u < 4; ++u) {
        int r = u * 16 + lr;
        int cg = lc ^ ((r >> 1) & 3);
        const unsigned short* g =
            src + (size_t)(i0 + r) * DSP + kc16 * 32 + cg * 8;
        __builtin_amdgcn_global_load_lds(
            (const __attribute__((address_space(1))) unsigned int*)g,
            (__attribute__((address_space(3))) unsigned int*)(dstb + u * 512),
            16, 0, 0);
      }
    } else {
#pragma unroll
      for (int u = 0; u < 8; ++u) {
        int r = u * 16 + lr;
        int cg = lc ^ ((r >> 1) & 3);
        const unsigned short* g =
            src + (size_t)(j0 + r) * DSP + kc16 * 32 + cg * 8;
        __builtin_amdgcn_global_load_lds(
            (const __attribute__((address_space(1))) unsigned int*)g,
            (__attribute__((address_space(3))) unsigned int*)(dstb + u * 512),
            16, 0, 0);
      }
    }
  };

  stage_fn(0, 0);
  __syncthreads();

  for (int kc = 0; kc < 16; ++kc) {
    int cur = kc & 1;
    if (kc < 15) stage_fn(kc + 1, cur ^ 1);
    const unsigned short* sb = st + cur * 12288;
    bf16x8 ah[2], al[2], bh[4], bl[4];
#pragma unroll
    for (int r = 0; r < 2; ++r) {
      int ra = wi + r * 16 + m16;
      int sa = kc8 ^ ((ra >> 1) & 3);
      ah[r] = *(const bf16x8*)&sb[ra * 32 + sa * 8];
      al[r] = *(const bf16x8*)&sb[2048 + ra * 32 + sa * 8];
    }
#pragma unroll
    for (int c = 0; c < 4; ++c) {
      int rb = wj + c * 16 + m16;
      int sb2 = kc8 ^ ((rb >> 1) & 3);
      bh[c] = *(const bf16x8*)&sb[4096 + rb * 32 + sb2 * 8];
      bl[c] = *(const bf16x8*)&sb[8192 + rb * 32 + sb2 * 8];
    }
#pragma unroll
    for (int r = 0; r < 2; ++r)
#pragma unroll
      for (int c = 0; c < 4; ++c) {
        acc[r][c] = __builtin_amdgcn_mfma_f32_16x16x32_bf16(ah[r], bh[c],
                                                            acc[r][c], 0, 0, 0);
        acc[r][c] = __builtin_amdgcn_mfma_f32_16x16x32_bf16(ah[r], bl[c],
                                                            acc[r][c], 0, 0, 0);
        acc[r][c] = __builtin_amdgcn_mfma_f32_16x16x32_bf16(al[r], bh[c],
                                                            acc[r][c], 0, 0, 0);
      }
    __syncthreads();
  }

#pragma unroll
  for (int r = 0; r < 2; ++r) {
#pragma unroll
    for (int c = 0; c < 4; ++c) {
      int lj = wj + c * 16 + m16;
      float p0v = p0[j0 + lj];
#pragma unroll
      for (int g = 0; g < 4; ++g) {
        int li = wi + r * 16 + kc8 * 4 + g;
        float z = q0[i0 + li] * p0v - acc[r][c][g];
        float zc = fmaxf(z, 1.0f + 1e-7f);
        float d = acoshf(zc);
        sout[li * 130 + lj] = -d * d;
      }
    }
  }
  __syncthreads();
#pragma unroll
  for (int p = 0; p < 8; ++p) {
    int row = p * 8 + (t >> 5);
    int col = (t & 31) * 4;
    f32x4 v = *(f32x4*)&sout[row * 130 + col];
    *(f32x4*)&S[(size_t)(i0 + row) * NC + j0 + col] = v;
  }
}

// ---------------- row stats: shift-free softmax, no atomics -----------------
__global__ __launch_bounds__(256) void k_rowstats(
    const float* __restrict__ S, float* __restrict__ rowZ,
    float* __restrict__ colp) {
  __shared__ float smc[4 * NC];
  int b = blockIdx.x;
  int t = threadIdx.x;
  int w = t >> 6, lane = t & 63;
  float cp[16] = {};
#pragma unroll
  for (int rr = 0; rr < 4; ++rr) {
    int i = b * 16 + w * 4 + rr;
    float e[16];
    float zs = 0.f;
#pragma unroll
    for (int seg = 0; seg < 4; ++seg) {
      float4 sv = *(const float4*)&S[(size_t)i * NC + seg * 256 + lane * 4];
      e[seg * 4 + 0] = expf(sv.x);
      e[seg * 4 + 1] = expf(sv.y);
      e[seg * 4 + 2] = expf(sv.z);
      e[seg * 4 + 3] = expf(sv.w);
      zs += e[seg * 4 + 0] + e[seg * 4 + 1] + e[seg * 4 + 2] + e[seg * 4 + 3];
    }
#pragma unroll
    for (int o = 32; o > 0; o >>= 1) zs += __shfl_xor(zs, o, 64);
    float inv = 1.0f / zs;
#pragma unroll
    for (int k2 = 0; k2 < 16; ++k2) cp[k2] += e[k2] * inv;
    if (lane == 0) rowZ[i] = zs;
  }
#pragma unroll
  for (int seg = 0; seg < 4; ++seg) {
    f32x4 v = {cp[seg * 4 + 0], cp[seg * 4 + 1], cp[seg * 4 + 2],
               cp[seg * 4 + 3]};
    *(f32x4*)&smc[w * NC + seg * 256 + lane * 4] = v;
  }
  __syncthreads();
  f32x4 a0 = *(f32x4*)&smc[0 * NC + t * 4];
  f32x4 a1 = *(f32x4*)&smc[1 * NC + t * 4];
  f32x4 a2 = *(f32x4*)&smc[2 * NC + t * 4];
  f32x4 a3 = *(f32x4*)&smc[3 * NC + t * 4];
  f32x4 sum = a0 + a1 + a2 + a3;
  *(f32x4*)&colp[(size_t)b * NC + t * 4] = sum;
}

// ---------------- column finalize: A_j from 256 partials --------------------
__global__ __launch_bounds__(256) void k_colfin(const float* __restrict__ colp,
                                                float* __restrict__ Avec) {
  __shared__ float sm[4][16];
  int b = blockIdx.x;
  int t = threadIdx.x;
  int c = t & 15;
  int pbase = t >> 4;
  int col = b * 16 + c;
  float v = 0.f;
#pragma unroll
  for (int q = 0; q < 16; ++q)
    v += colp[(size_t)(pbase + q * 16) * NC + col];
  v += __shfl_xor(v, 16, 64);
  v += __shfl_xor(v, 32, 64);
  int w = t >> 6, lane = t & 63;
  if (lane < 16) sm[w][lane] = v;
  __syncthreads();
  if (t < 16) {
    float s = sm[0][t] + sm[1][t] + sm[2][t] + sm[3][t];
    float Pm = s * (1.0f / NQ);
    Avec[b * 16 + t] = logf(Pm + 1e-8f) + Pm / (Pm + 1e-8f);
  }
}

// ---------------- G write v3: 1024 threads, one row per wave ----------------
__global__ __launch_bounds__(1024) void k_gwrite(
    const float* __restrict__ S, const float* __restrict__ rowZ,
    const float* __restrict__ Avec, unsigned short* __restrict__ Gth,
    unsigned short* __restrict__ Gtl) {
  __shared__ unsigned short LG[2][16][1032];
  int b = blockIdx.x;
  int t = threadIdx.x;
  int w = t >> 6, lane = t & 63;

  float a[16];
#pragma unroll
  for (int seg = 0; seg < 4; ++seg) {
    f32x4 av = *(const f32x4*)&Avec[seg * 256 + lane * 4];
    a[seg * 4 + 0] = av[0];
    a[seg * 4 + 1] = av[1];
    a[seg * 4 + 2] = av[2];
    a[seg * 4 + 3] = av[3];
  }

  int i = b * 16 + w;
  float Z = rowZ[i];
  float inv = 1.0f / Z;
  float lnZ = logf(Z);
  float s[16], p[16];
  float u = 0.f, r = 0.f;
#pragma unroll
  for (int seg = 0; seg < 4; ++seg) {
    float4 sv = *(const float4*)&S[(size_t)i * NC + seg * 256 + lane * 4];
    float ss[4] = {sv.x, sv.y, sv.z, sv.w};
#pragma unroll
    for (int jj = 0; jj < 4; ++jj) {
      int k2 = seg * 4 + jj;
      s[k2] = ss[jj];
      p[k2] = expf(ss[jj]) * inv;
      float B = ss[jj] - lnZ + 1.0f;
      u += p[k2] * a[k2];
      r += p[k2] * B;
    }
  }
#pragma unroll
  for (int o = 32; o > 0; o >>= 1) {
    u += __shfl_xor(u, o, 64);
    r += __shfl_xor(r, o, 64);
  }
  float ti = (u - r) * (1.0f / NQ);
#pragma unroll
  for (int seg = 0; seg < 4; ++seg) {
    ushort4v gh, gl;
#pragma unroll
    for (int jj = 0; jj < 4; ++jj) {
      int k2 = seg * 4 + jj;
      float B = s[k2] - lnZ + 1.0f;
      float gg = (a[k2] - B) * (1.0f / NQ);
      float dS = p[k2] * (gg - ti);
      float d = sqrtf(fmaxf(-s[k2], 0.0f));
      float ed = expf(d);
      float sh = 0.5f * (ed - 1.0f / ed);
      float gv = (s[k2] < -2.1e-7f) ? dS * (-2.0f * d) / sh : 0.0f;
      unsigned short hh, ll;
      splitbf(gv, hh, ll);
      gh[jj] = hh;
      gl[jj] = ll;
    }
    *(ushort4v*)&LG[0][w][seg * 256 + lane * 4] = gh;
    *(ushort4v*)&LG[1][w][seg * 256 + lane * 4] = gl;
  }
  __syncthreads();
  ushort8v h0, h1, l0, l1;
#pragma unroll
  for (int ii = 0; ii < 8; ++ii) {
    h0[ii] = LG[0][ii][t];
    h1[ii] = LG[0][8 + ii][t];
    l0[ii] = LG[1][ii][t];
    l1[ii] = LG[1][8 + ii][t];
  }
  size_t base = ((size_t)b * 1024 + t) * 16;
  *(ushort8v*)&Gth[base] = h0;
  *(ushort8v*)&Gth[base + 8] = h1;
  *(ushort8v*)&Gtl[base] = l0;
  *(ushort8v*)&Gtl[base + 8] = l1;
}

// ---------------- GEMM2 v6: 64j x 64k tile, NSPLIT=4, 32KB LDS --------------
// gradp[split][j][k] = sum_{i in split(1024 rows)} G[i][j]*Q[i][k]
// Grid 512 = 4 split x 16 j x 8 k; b&7 fixes split -> one split per XCD.
__global__ __launch_bounds__(256) void k_gemm2(
    const unsigned short* __restrict__ Gth, const unsigned short* __restrict__ Gtl,
    const unsigned short* __restrict__ Qth, const unsigned short* __restrict__ Qtl,
    float* __restrict__ gradp) {
  __shared__ __align__(16) char smem[32768];
  unsigned short* st = (unsigned short*)smem;
  float* sout = (float*)smem;  // 64x68 f32

  int b = blockIdx.x;
  int split = b & 3;
  int m = b >> 2;
  int j0 = (m & 15) * 64;
  int k0 = (m >> 4) * 64;

  int t = threadIdx.x;
  int lane = t & 63;
  int w = t >> 6;
  int wj = (w & 1) * 32, wk = (w >> 1) * 32;
  int m16 = lane & 15;
  int g4 = lane >> 4;
  int ic2r = g4 >> 1, hr = g4 & 1;

  const unsigned short* src = (w == 0) ? Gth : (w == 1) ? Gtl
                              : (w == 2) ? Qth : Qtl;
  int colbase = (w < 2) ? j0 : k0;
  int nrow = (w < 2) ? NC : DSP;
  int arrOff = w * 2048;

  f32x4 acc[2][2];
#pragma unroll
  for (int r = 0; r < 2; ++r)
#pragma unroll
    for (int c = 0; c < 2; ++c) acc[r][c] = (f32x4){0.f, 0.f, 0.f, 0.f};

  auto stage_fn = [&](int kc, int buf) {
    int ic0 = split * 64 + kc * 2;
    unsigned short* dstb = st + buf * 8192 + arrOff;
#pragma unroll
    for (int u = 0; u < 4; ++u) {
      int ic2 = u >> 1, h = u & 1;
      const unsigned short* g =
          src + ((size_t)(ic0 + ic2) * nrow + colbase + lane) * 16 + h * 8;
      __builtin_amdgcn_global_load_lds(
          (const __attribute__((address_space(1))) unsigned int*)g,
          (__attribute__((address_space(3))) unsigned int*)(dstb + ic2 * 1024 +
                                                            h * 512),
          16, 0, 0);
    }
  };

  stage_fn(0, 0);
  __syncthreads();

  for (int kc = 0; kc < 32; ++kc) {
    int cur = kc & 1;
    if (kc < 31) stage_fn(kc + 1, cur ^ 1);
    const unsigned short* sb = st + cur * 8192;
    bf16x8 ah[2], al[2], bh[2], bl[2];
#pragma unroll
    for (int r = 0; r < 2; ++r) {
      int ja = wj + r * 16 + m16;
      ah[r] = *(const bf16x8*)&sb[ic2r * 1024 + hr * 512 + ja * 8];
      al[r] = *(const bf16x8*)&sb[2048 + ic2r * 1024 + hr * 512 + ja * 8];
      int kb = wk + r * 16 + m16;
      bh[r] = *(const bf16x8*)&sb[4096 + ic2r * 1024 + hr * 512 + kb * 8];
      bl[r] = *(const bf16x8*)&sb[6144 + ic2r * 1024 + hr * 512 + kb * 8];
    }
#pragma unroll
    for (int r = 0; r < 2; ++r)
#pragma unroll
      for (int c = 0; c < 2; ++c) {
        acc[r][c] = __builtin_amdgcn_mfma_f32_16x16x32_bf16(ah[r], bh[c],
                                                            acc[r][c], 0, 0, 0);
        acc[r][c] = __builtin_amdgcn_mfma_f32_16x16x32_bf16(ah[r], bl[c],
                                                            acc[r][c], 0, 0, 0);
        acc[r][c] = __builtin_amdgcn_mfma_f32_16x16x32_bf16(al[r], bh[c],
                                                            acc[r][c], 0, 0, 0);
      }
    __syncthreads();
  }

#pragma unroll
  for (int r = 0; r < 2; ++r) {
#pragma unroll
    for (int c = 0; c < 2; ++c) {
      int lk = wk + c * 16 + m16;
#pragma unroll
      for (int g = 0; g < 4; ++g) {
        int lj = wj + r * 16 + g4 * 4 + g;
        sout[lj * 68 + lk] = acc[r][c][g];
      }
    }
  }
  __syncthreads();
  float* gp = gradp + (size_t)split * NC * DSP;
#pragma unroll
  for (int p = 0; p < 4; ++p) {
    int row = p * 16 + (t >> 4);
    int col = (t & 15) * 4;
    f32x4 v = *(f32x4*)&sout[row * 68 + col];
    *(f32x4*)&gp[(size_t)(j0 + row) * DSP + k0 + col] = v;
  }
}

// ---------------- Adam: reduce 4 split partials; WD + projection ------------
__global__ __launch_bounds__(256) void k_adam(
    const float* __restrict__ gradp, float* __restrict__ Ps,
    float* __restrict__ mb, float* __restrict__ vb, float* __restrict__ p0,
    unsigned short* __restrict__ Ph, unsigned short* __restrict__ Pl,
    float bc1, float bc2) {
  __shared__ float sm[4];
  int j = blockIdx.x;
  int t = threadIdx.x;
  float ss = 0.f;
#pragma unroll
  for (int h = 0; h < 2; ++h) {
    int k = t + h * 256;
    size_t idx = (size_t)j * DSP + k;
    float g = 0.f;
#pragma unroll
    for (int sp = 0; sp < NSPLIT; ++sp)
      g += gradp[(size_t)sp * NC * DSP + idx];
    g = -g;
    float m = 0.9f * mb[idx] + 0.1f * g;
    float v = 0.999f * vb[idx] + 0.001f * g * g;
    mb[idx] = m;
    vb[idx] = v;
    float mh = m / bc1;
    float vh = v / bc2;
    float s = Ps[idx] * (1.0f - 0.1f * 0.01f) - 0.1f * mh / (sqrtf(vh) + 1e-8f);
    Ps[idx] = s;
    unsigned short hh, ll;
    splitbf(s, hh, ll);
    Ph[idx] = hh;
    Pl[idx] = ll;
    ss += s * s;
  }
#pragma unroll
  for (int o = 32; o > 0; o >>= 1) ss += __shfl_xor(ss, o, 64);
  int w = t >> 6;
  if ((t & 63) == 0) sm[w] = ss;
  __syncthreads();
  if (t == 0) p0[j] = sqrtf(1.0f + sm[0] + sm[1] + sm[2] + sm[3]);
}

// ---------------- output assembly ------------------------------------------
__global__ void k_out(const float* __restrict__ p0, const float* __restrict__ Ps,
                      float* __restrict__ out) {
  int tid = blockIdx.x * blockDim.x + threadIdx.x;
  int stride = gridDim.x * blockDim.x;
  for (int idx = tid; idx < NC * AMB; idx += stride) {
    int j = idx / AMB;
    int c = idx - j * AMB;
    out[idx] = (c == 0) ? p0[j] : Ps[(size_t)j * DSP + c - 1];
  }
}

extern "C" void kernel_launch(void* const* d_in, const int* in_sizes, int n_in,
                              void* d_out, int out_size, void* d_ws,
                              size_t ws_size, hipStream_t stream) {
  const float* protos_in = (const float*)d_in[0];
  const float* query_in = (const float*)d_in[1];

  char* wp = (char*)d_ws;
  auto alloc = [&](size_t bytes) {
    char* p = wp;
    wp += (bytes + 255) & ~(size_t)255;
    return p;
  };
  float* q0 = (float*)alloc(NQ * 4);
  float* p0 = (float*)alloc(NC * 4);
  float* Ps = (float*)alloc((size_t)NC * DSP * 4);
  float* mb = (float*)alloc((size_t)NC * DSP * 4);
  float* vb = (float*)alloc((size_t)NC * DSP * 4);
  float* S = (float*)alloc((size_t)NQ * NC * 4);
  float* rowZ = (float*)alloc(NQ * 4);
  float* colp = (float*)alloc((size_t)NPART * NC * 4);
  float* Avec = (float*)alloc(NC * 4);
  float* gradp = (float*)alloc((size_t)NSPLIT * NC * DSP * 4);
  unsigned short* Qh = (unsigned short*)alloc((size_t)NQ * DSP * 2);
  unsigned short* Ql = (unsigned short*)alloc((size_t)NQ * DSP * 2);
  unsigned short* Qth = (unsigned short*)alloc((size_t)NQ * DSP * 2);
  unsigned short* Qtl = (unsigned short*)alloc((size_t)NQ * DSP * 2);
  unsigned short* Ph = (unsigned short*)alloc((size_t)NC * DSP * 2);
  unsigned short* Pl = (unsigned short*)alloc((size_t)NC * DSP * 2);
  unsigned short* Gth = (unsigned short*)alloc((size_t)NQ * NC * 2);
  unsigned short* Gtl = (unsigned short*)alloc((size_t)NQ * NC * 2);

  hipMemsetAsync(mb, 0, (size_t)NC * DSP * 4, stream);
  hipMemsetAsync(vb, 0, (size_t)NC * DSP * 4, stream);
  k_setup_q<<<256, 256, 0, stream>>>(query_in, q0, Qh, Ql, Qth, Qtl);
  k_setup_p<<<128, 256, 0, stream>>>(protos_in, p0, Ps, Ph, Pl);

  for (int it = 1; it <= NITER; ++it) {
    float bc1 = 1.0f - powf(0.9f, (float)it);
    float bc2 = 1.0f - powf(0.999f, (float)it);
    k_gemm1<<<512, 256, 0, stream>>>(Qh, Ql, Ph, Pl, q0, p0, S);
    k_rowstats<<<NPART, 256, 0, stream>>>(S, rowZ, colp);
    k_colfin<<<64, 256, 0, stream>>>(colp, Avec);
    k_gwrite<<<256, 1024, 0, stream>>>(S, rowZ, Avec, Gth, Gtl);
    k_gemm2<<<512, 256, 0, stream>>>(Gth, Gtl, Qth, Qtl, gradp);
    k_adam<<<NC, 256, 0, stream>>>(gradp, Ps, mb, vb, p0, Ph, Pl, bc1, bc2);
  }
  k_out<<<512, 256, 0, stream>>>(p0, Ps, (float*)d_out);
}

// Round 11
// 1703.379 us; speedup vs baseline: 1.0162x; 1.0162x over previous
//
#include <hip/hip_runtime.h>
#include <math.h>

#define NQ 4096
#define NC 1024
#define DSP 512
#define AMB 513
#define NITER 20
#define NPART 256
#define NSPLIT 4

typedef __bf16 bf16x8 __attribute__((ext_vector_type(8)));
typedef float f32x4 __attribute__((ext_vector_type(4)));
typedef unsigned short ushort4v __attribute__((ext_vector_type(4)));
typedef unsigned short ushort8v __attribute__((ext_vector_type(8)));

// ---- two-term bf16 split: x ~= hi + lo, error ~2^-18 relative --------------
__device__ __forceinline__ void splitbf(float x, unsigned short& h,
                                        unsigned short& l) {
  unsigned u = __float_as_uint(x);
  unsigned hb = (u + 0x7fffu + ((u >> 16) & 1u)) & 0xffff0000u;
  float fh = __uint_as_float(hb);
  float r = x - fh;
  unsigned ur = __float_as_uint(r);
  h = (unsigned short)(hb >> 16);
  l = (unsigned short)((ur + 0x7fffu + ((ur >> 16) & 1u)) >> 16);
}

// ---------------- setup ------------------------------------------------------
__global__ void k_setup_q(const float* __restrict__ q, float* __restrict__ q0,
                          unsigned short* __restrict__ Qh,
                          unsigned short* __restrict__ Ql,
                          unsigned short* __restrict__ Qth,
                          unsigned short* __restrict__ Qtl) {
  int tid = blockIdx.x * blockDim.x + threadIdx.x;
  int stride = gridDim.x * blockDim.x;
  for (int idx = tid; idx < NQ * DSP; idx += stride) {
    int i = idx >> 9, k = idx & 511;
    float v = q[i * AMB + 1 + k];
    unsigned short h, l;
    splitbf(v, h, l);
    Qh[idx] = h;
    Ql[idx] = l;
    size_t tq = ((size_t)(i >> 4) * DSP + k) * 16 + (i & 15);
    Qth[tq] = h;
    Qtl[tq] = l;
  }
  for (int i = tid; i < NQ; i += stride) q0[i] = q[i * AMB];
}

__global__ void k_setup_p(const float* __restrict__ p, float* __restrict__ p0,
                          float* __restrict__ Ps,
                          unsigned short* __restrict__ Ph,
                          unsigned short* __restrict__ Pl) {
  int tid = blockIdx.x * blockDim.x + threadIdx.x;
  int stride = gridDim.x * blockDim.x;
  for (int idx = tid; idx < NC * DSP; idx += stride) {
    int j = idx >> 9, k = idx & 511;
    float v = p[j * AMB + 1 + k];
    Ps[idx] = v;
    splitbf(v, Ph[idx], Pl[idx]);
  }
  for (int j = tid; j < NC; j += stride) p0[j] = p[j * AMB];
}

// ---------------- GEMM1 v4: 64x64 tile, 32KB LDS -> 4 blocks/CU -------------
// S[i,j] = -arccosh(max(q0_i*p0_j - Q_i.P_j, 1+1e-7))^2
// Grid 1024 = 64 i-panels x 16 j-panels; XCD owns 8 i-panels (~1MB Q) + all P
// (2MB) -> 3MB per-XCD L2 set. Wave: 32i x 32j quadrant.
__global__ __launch_bounds__(256) void k_gemm1(
    const unsigned short* __restrict__ Qh, const unsigned short* __restrict__ Ql,
    const unsigned short* __restrict__ Ph, const unsigned short* __restrict__ Pl,
    const float* __restrict__ q0, const float* __restrict__ p0,
    float* __restrict__ S) {
  __shared__ __align__(16) char smem[32768];
  unsigned short* st = (unsigned short*)smem;
  float* sout = (float*)smem;  // 64x68 f32 = 17408 B (after K-loop)

  int b = blockIdx.x;
  int xcd = b & 7, m = b >> 3;          // m 0..127
  int i0 = (xcd * 8 + (m >> 4)) * 64;   // 64 i-panels
  int j0 = (m & 15) * 64;               // 16 j-panels

  int t = threadIdx.x;
  int lane = t & 63;
  int w = t >> 6;
  int wi = (w & 1) * 32, wj = (w >> 1) * 32;
  int m16 = lane & 15;
  int kc8 = lane >> 4;

  const unsigned short* src = (w == 0) ? Qh : (w == 1) ? Ql : (w == 2) ? Ph : Pl;
  int rowbase = (w < 2) ? i0 : j0;
  int arrOff = w * 2048;
  int lr = lane >> 2;  // 0..15
  int lc = lane & 3;   // 16B chunk slot

  f32x4 acc[2][2];
#pragma unroll
  for (int r = 0; r < 2; ++r)
#pragma unroll
    for (int c = 0; c < 2; ++c) acc[r][c] = (f32x4){0.f, 0.f, 0.f, 0.f};

  auto stage_fn = [&](int kc16, int buf) {
    unsigned short* dstb = st + buf * 8192 + arrOff;
#pragma unroll
    for (int u = 0; u < 4; ++u) {
      int r = u * 16 + lr;
      int cg = lc ^ ((r >> 1) & 3);
      const unsigned short* g =
          src + (size_t)(rowbase + r) * DSP + kc16 * 32 + cg * 8;
      __builtin_amdgcn_global_load_lds(
          (const __attribute__((address_space(1))) unsigned int*)g,
          (__attribute__((address_space(3))) unsigned int*)(dstb + u * 512),
          16, 0, 0);
    }
  };

  stage_fn(0, 0);
  __syncthreads();

  for (int kc = 0; kc < 16; ++kc) {
    int cur = kc & 1;
    if (kc < 15) stage_fn(kc + 1, cur ^ 1);
    const unsigned short* sb = st + cur * 8192;
    bf16x8 ah[2], al[2], bh[2], bl[2];
#pragma unroll
    for (int r = 0; r < 2; ++r) {
      int ra = wi + r * 16 + m16;
      int sa = kc8 ^ ((ra >> 1) & 3);
      ah[r] = *(const bf16x8*)&sb[ra * 32 + sa * 8];
      al[r] = *(const bf16x8*)&sb[2048 + ra * 32 + sa * 8];
      int rb = wj + r * 16 + m16;
      int sb2 = kc8 ^ ((rb >> 1) & 3);
      bh[r] = *(const bf16x8*)&sb[4096 + rb * 32 + sb2 * 8];
      bl[r] = *(const bf16x8*)&sb[6144 + rb * 32 + sb2 * 8];
    }
#pragma unroll
    for (int r = 0; r < 2; ++r)
#pragma unroll
      for (int c = 0; c < 2; ++c) {
        acc[r][c] = __builtin_amdgcn_mfma_f32_16x16x32_bf16(ah[r], bh[c],
                                                            acc[r][c], 0, 0, 0);
        acc[r][c] = __builtin_amdgcn_mfma_f32_16x16x32_bf16(ah[r], bl[c],
                                                            acc[r][c], 0, 0, 0);
        acc[r][c] = __builtin_amdgcn_mfma_f32_16x16x32_bf16(al[r], bh[c],
                                                            acc[r][c], 0, 0, 0);
      }
    __syncthreads();
  }

  // epilogue: -acosh^2 -> sout (64x68) -> coalesced 256B-row stores
#pragma unroll
  for (int r = 0; r < 2; ++r) {
#pragma unroll
    for (int c = 0; c < 2; ++c) {
      int lj = wj + c * 16 + m16;
      float p0v = p0[j0 + lj];
#pragma unroll
      for (int g = 0; g < 4; ++g) {
        int li = wi + r * 16 + kc8 * 4 + g;
        float z = q0[i0 + li] * p0v - acc[r][c][g];
        float zc = fmaxf(z, 1.0f + 1e-7f);
        float d = acoshf(zc);
        sout[li * 68 + lj] = -d * d;
      }
    }
  }
  __syncthreads();
#pragma unroll
  for (int p = 0; p < 4; ++p) {
    int row = p * 16 + (t >> 4);
    int col = (t & 15) * 4;
    f32x4 v = *(f32x4*)&sout[row * 68 + col];
    *(f32x4*)&S[(size_t)(i0 + row) * NC + j0 + col] = v;
  }
}

// ---------------- row stats: shift-free softmax, no atomics -----------------
__global__ __launch_bounds__(256) void k_rowstats(
    const float* __restrict__ S, float* __restrict__ rowZ,
    float* __restrict__ colp) {
  __shared__ float smc[4 * NC];
  int b = blockIdx.x;
  int t = threadIdx.x;
  int w = t >> 6, lane = t & 63;
  float cp[16] = {};
#pragma unroll
  for (int rr = 0; rr < 4; ++rr) {
    int i = b * 16 + w * 4 + rr;
    float e[16];
    float zs = 0.f;
#pragma unroll
    for (int seg = 0; seg < 4; ++seg) {
      float4 sv = *(const float4*)&S[(size_t)i * NC + seg * 256 + lane * 4];
      e[seg * 4 + 0] = expf(sv.x);
      e[seg * 4 + 1] = expf(sv.y);
      e[seg * 4 + 2] = expf(sv.z);
      e[seg * 4 + 3] = expf(sv.w);
      zs += e[seg * 4 + 0] + e[seg * 4 + 1] + e[seg * 4 + 2] + e[seg * 4 + 3];
    }
#pragma unroll
    for (int o = 32; o > 0; o >>= 1) zs += __shfl_xor(zs, o, 64);
    float inv = 1.0f / zs;
#pragma unroll
    for (int k2 = 0; k2 < 16; ++k2) cp[k2] += e[k2] * inv;
    if (lane == 0) rowZ[i] = zs;
  }
#pragma unroll
  for (int seg = 0; seg < 4; ++seg) {
    f32x4 v = {cp[seg * 4 + 0], cp[seg * 4 + 1], cp[seg * 4 + 2],
               cp[seg * 4 + 3]};
    *(f32x4*)&smc[w * NC + seg * 256 + lane * 4] = v;
  }
  __syncthreads();
  f32x4 a0 = *(f32x4*)&smc[0 * NC + t * 4];
  f32x4 a1 = *(f32x4*)&smc[1 * NC + t * 4];
  f32x4 a2 = *(f32x4*)&smc[2 * NC + t * 4];
  f32x4 a3 = *(f32x4*)&smc[3 * NC + t * 4];
  f32x4 sum = a0 + a1 + a2 + a3;
  *(f32x4*)&colp[(size_t)b * NC + t * 4] = sum;
}

// ---------------- column finalize: A_j from 256 partials --------------------
__global__ __launch_bounds__(256) void k_colfin(const float* __restrict__ colp,
                                                float* __restrict__ Avec) {
  __shared__ float sm[4][16];
  int b = blockIdx.x;
  int t = threadIdx.x;
  int c = t & 15;
  int pbase = t >> 4;
  int col = b * 16 + c;
  float v = 0.f;
#pragma unroll
  for (int q = 0; q < 16; ++q)
    v += colp[(size_t)(pbase + q * 16) * NC + col];
  v += __shfl_xor(v, 16, 64);
  v += __shfl_xor(v, 32, 64);
  int w = t >> 6, lane = t & 63;
  if (lane < 16) sm[w][lane] = v;
  __syncthreads();
  if (t < 16) {
    float s = sm[0][t] + sm[1][t] + sm[2][t] + sm[3][t];
    float Pm = s * (1.0f / NQ);
    Avec[b * 16 + t] = logf(Pm + 1e-8f) + Pm / (Pm + 1e-8f);
  }
}

// ---------------- G write v3: 1024 threads, one row per wave ----------------
__global__ __launch_bounds__(1024) void k_gwrite(
    const float* __restrict__ S, const float* __restrict__ rowZ,
    const float* __restrict__ Avec, unsigned short* __restrict__ Gth,
    unsigned short* __restrict__ Gtl) {
  __shared__ unsigned short LG[2][16][1032];
  int b = blockIdx.x;
  int t = threadIdx.x;
  int w = t >> 6, lane = t & 63;

  float a[16];
#pragma unroll
  for (int seg = 0; seg < 4; ++seg) {
    f32x4 av = *(const f32x4*)&Avec[seg * 256 + lane * 4];
    a[seg * 4 + 0] = av[0];
    a[seg * 4 + 1] = av[1];
    a[seg * 4 + 2] = av[2];
    a[seg * 4 + 3] = av[3];
  }

  int i = b * 16 + w;
  float Z = rowZ[i];
  float inv = 1.0f / Z;
  float lnZ = logf(Z);
  float s[16], p[16];
  float u = 0.f, r = 0.f;
#pragma unroll
  for (int seg = 0; seg < 4; ++seg) {
    float4 sv = *(const float4*)&S[(size_t)i * NC + seg * 256 + lane * 4];
    float ss[4] = {sv.x, sv.y, sv.z, sv.w};
#pragma unroll
    for (int jj = 0; jj < 4; ++jj) {
      int k2 = seg * 4 + jj;
      s[k2] = ss[jj];
      p[k2] = expf(ss[jj]) * inv;
      float B = ss[jj] - lnZ + 1.0f;
      u += p[k2] * a[k2];
      r += p[k2] * B;
    }
  }
#pragma unroll
  for (int o = 32; o > 0; o >>= 1) {
    u += __shfl_xor(u, o, 64);
    r += __shfl_xor(r, o, 64);
  }
  float ti = (u - r) * (1.0f / NQ);
#pragma unroll
  for (int seg = 0; seg < 4; ++seg) {
    ushort4v gh, gl;
#pragma unroll
    for (int jj = 0; jj < 4; ++jj) {
      int k2 = seg * 4 + jj;
      float B = s[k2] - lnZ + 1.0f;
      float gg = (a[k2] - B) * (1.0f / NQ);
      float dS = p[k2] * (gg - ti);
      float d = sqrtf(fmaxf(-s[k2], 0.0f));
      float ed = expf(d);
      float sh = 0.5f * (ed - 1.0f / ed);
      float gv = (s[k2] < -2.1e-7f) ? dS * (-2.0f * d) / sh : 0.0f;
      unsigned short hh, ll;
      splitbf(gv, hh, ll);
      gh[jj] = hh;
      gl[jj] = ll;
    }
    *(ushort4v*)&LG[0][w][seg * 256 + lane * 4] = gh;
    *(ushort4v*)&LG[1][w][seg * 256 + lane * 4] = gl;
  }
  __syncthreads();
  ushort8v h0, h1, l0, l1;
#pragma unroll
  for (int ii = 0; ii < 8; ++ii) {
    h0[ii] = LG[0][ii][t];
    h1[ii] = LG[0][8 + ii][t];
    l0[ii] = LG[1][ii][t];
    l1[ii] = LG[1][8 + ii][t];
  }
  size_t base = ((size_t)b * 1024 + t) * 16;
  *(ushort8v*)&Gth[base] = h0;
  *(ushort8v*)&Gth[base + 8] = h1;
  *(ushort8v*)&Gtl[base] = l0;
  *(ushort8v*)&Gtl[base + 8] = l1;
}

// ---------------- GEMM2 v6: 64j x 64k tile, NSPLIT=4, 32KB LDS --------------
__global__ __launch_bounds__(256) void k_gemm2(
    const unsigned short* __restrict__ Gth, const unsigned short* __restrict__ Gtl,
    const unsigned short* __restrict__ Qth, const unsigned short* __restrict__ Qtl,
    float* __restrict__ gradp) {
  __shared__ __align__(16) char smem[32768];
  unsigned short* st = (unsigned short*)smem;
  float* sout = (float*)smem;  // 64x68 f32

  int b = blockIdx.x;
  int split = b & 3;
  int m = b >> 2;
  int j0 = (m & 15) * 64;
  int k0 = (m >> 4) * 64;

  int t = threadIdx.x;
  int lane = t & 63;
  int w = t >> 6;
  int wj = (w & 1) * 32, wk = (w >> 1) * 32;
  int m16 = lane & 15;
  int g4 = lane >> 4;
  int ic2r = g4 >> 1, hr = g4 & 1;

  const unsigned short* src = (w == 0) ? Gth : (w == 1) ? Gtl
                              : (w == 2) ? Qth : Qtl;
  int colbase = (w < 2) ? j0 : k0;
  int nrow = (w < 2) ? NC : DSP;
  int arrOff = w * 2048;

  f32x4 acc[2][2];
#pragma unroll
  for (int r = 0; r < 2; ++r)
#pragma unroll
    for (int c = 0; c < 2; ++c) acc[r][c] = (f32x4){0.f, 0.f, 0.f, 0.f};

  auto stage_fn = [&](int kc, int buf) {
    int ic0 = split * 64 + kc * 2;
    unsigned short* dstb = st + buf * 8192 + arrOff;
#pragma unroll
    for (int u = 0; u < 4; ++u) {
      int ic2 = u >> 1, h = u & 1;
      const unsigned short* g =
          src + ((size_t)(ic0 + ic2) * nrow + colbase + lane) * 16 + h * 8;
      __builtin_amdgcn_global_load_lds(
          (const __attribute__((address_space(1))) unsigned int*)g,
          (__attribute__((address_space(3))) unsigned int*)(dstb + ic2 * 1024 +
                                                            h * 512),
          16, 0, 0);
    }
  };

  stage_fn(0, 0);
  __syncthreads();

  for (int kc = 0; kc < 32; ++kc) {
    int cur = kc & 1;
    if (kc < 31) stage_fn(kc + 1, cur ^ 1);
    const unsigned short* sb = st + cur * 8192;
    bf16x8 ah[2], al[2], bh[2], bl[2];
#pragma unroll
    for (int r = 0; r < 2; ++r) {
      int ja = wj + r * 16 + m16;
      ah[r] = *(const bf16x8*)&sb[ic2r * 1024 + hr * 512 + ja * 8];
      al[r] = *(const bf16x8*)&sb[2048 + ic2r * 1024 + hr * 512 + ja * 8];
      int kb = wk + r * 16 + m16;
      bh[r] = *(const bf16x8*)&sb[4096 + ic2r * 1024 + hr * 512 + kb * 8];
      bl[r] = *(const bf16x8*)&sb[6144 + ic2r * 1024 + hr * 512 + kb * 8];
    }
#pragma unroll
    for (int r = 0; r < 2; ++r)
#pragma unroll
      for (int c = 0; c < 2; ++c) {
        acc[r][c] = __builtin_amdgcn_mfma_f32_16x16x32_bf16(ah[r], bh[c],
                                                            acc[r][c], 0, 0, 0);
        acc[r][c] = __builtin_amdgcn_mfma_f32_16x16x32_bf16(ah[r], bl[c],
                                                            acc[r][c], 0, 0, 0);
        acc[r][c] = __builtin_amdgcn_mfma_f32_16x16x32_bf16(al[r], bh[c],
                                                            acc[r][c], 0, 0, 0);
      }
    __syncthreads();
  }

#pragma unroll
  for (int r = 0; r < 2; ++r) {
#pragma unroll
    for (int c = 0; c < 2; ++c) {
      int lk = wk + c * 16 + m16;
#pragma unroll
      for (int g = 0; g < 4; ++g) {
        int lj = wj + r * 16 + g4 * 4 + g;
        sout[lj * 68 + lk] = acc[r][c][g];
      }
    }
  }
  __syncthreads();
  float* gp = gradp + (size_t)split * NC * DSP;
#pragma unroll
  for (int p = 0; p < 4; ++p) {
    int row = p * 16 + (t >> 4);
    int col = (t & 15) * 4;
    f32x4 v = *(f32x4*)&sout[row * 68 + col];
    *(f32x4*)&gp[(size_t)(j0 + row) * DSP + k0 + col] = v;
  }
}

// ---------------- Adam: reduce 4 split partials; WD + projection ------------
__global__ __launch_bounds__(256) void k_adam(
    const float* __restrict__ gradp, float* __restrict__ Ps,
    float* __restrict__ mb, float* __restrict__ vb, float* __restrict__ p0,
    unsigned short* __restrict__ Ph, unsigned short* __restrict__ Pl,
    float bc1, float bc2) {
  __shared__ float sm[4];
  int j = blockIdx.x;
  int t = threadIdx.x;
  float ss = 0.f;
#pragma unroll
  for (int h = 0; h < 2; ++h) {
    int k = t + h * 256;
    size_t idx = (size_t)j * DSP + k;
    float g = 0.f;
#pragma unroll
    for (int sp = 0; sp < NSPLIT; ++sp)
      g += gradp[(size_t)sp * NC * DSP + idx];
    g = -g;
    float m = 0.9f * mb[idx] + 0.1f * g;
    float v = 0.999f * vb[idx] + 0.001f * g * g;
    mb[idx] = m;
    vb[idx] = v;
    float mh = m / bc1;
    float vh = v / bc2;
    float s = Ps[idx] * (1.0f - 0.1f * 0.01f) - 0.1f * mh / (sqrtf(vh) + 1e-8f);
    Ps[idx] = s;
    unsigned short hh, ll;
    splitbf(s, hh, ll);
    Ph[idx] = hh;
    Pl[idx] = ll;
    ss += s * s;
  }
#pragma unroll
  for (int o = 32; o > 0; o >>= 1) ss += __shfl_xor(ss, o, 64);
  int w = t >> 6;
  if ((t & 63) == 0) sm[w] = ss;
  __syncthreads();
  if (t == 0) p0[j] = sqrtf(1.0f + sm[0] + sm[1] + sm[2] + sm[3]);
}

// ---------------- output assembly ------------------------------------------
__global__ void k_out(const float* __restrict__ p0, const float* __restrict__ Ps,
                      float* __restrict__ out) {
  int tid = blockIdx.x * blockDim.x + threadIdx.x;
  int stride = gridDim.x * blockDim.x;
  for (int idx = tid; idx < NC * AMB; idx += stride) {
    int j = idx / AMB;
    int c = idx - j * AMB;
    out[idx] = (c == 0) ? p0[j] : Ps[(size_t)j * DSP + c - 1];
  }
}

extern "C" void kernel_launch(void* const* d_in, const int* in_sizes, int n_in,
                              void* d_out, int out_size, void* d_ws,
                              size_t ws_size, hipStream_t stream) {
  const float* protos_in = (const float*)d_in[0];
  const float* query_in = (const float*)d_in[1];

  char* wp = (char*)d_ws;
  auto alloc = [&](size_t bytes) {
    char* p = wp;
    wp += (bytes + 255) & ~(size_t)255;
    return p;
  };
  float* q0 = (float*)alloc(NQ * 4);
  float* p0 = (float*)alloc(NC * 4);
  float* Ps = (float*)alloc((size_t)NC * DSP * 4);
  float* mb = (float*)alloc((size_t)NC * DSP * 4);
  float* vb = (float*)alloc((size_t)NC * DSP * 4);
  float* S = (float*)alloc((size_t)NQ * NC * 4);
  float* rowZ = (float*)alloc(NQ * 4);
  float* colp = (float*)alloc((size_t)NPART * NC * 4);
  float* Avec = (float*)alloc(NC * 4);
  float* gradp = (float*)alloc((size_t)NSPLIT * NC * DSP * 4);
  unsigned short* Qh = (unsigned short*)alloc((size_t)NQ * DSP * 2);
  unsigned short* Ql = (unsigned short*)alloc((size_t)NQ * DSP * 2);
  unsigned short* Qth = (unsigned short*)alloc((size_t)NQ * DSP * 2);
  unsigned short* Qtl = (unsigned short*)alloc((size_t)NQ * DSP * 2);
  unsigned short* Ph = (unsigned short*)alloc((size_t)NC * DSP * 2);
  unsigned short* Pl = (unsigned short*)alloc((size_t)NC * DSP * 2);
  unsigned short* Gth = (unsigned short*)alloc((size_t)NQ * NC * 2);
  unsigned short* Gtl = (unsigned short*)alloc((size_t)NQ * NC * 2);

  hipMemsetAsync(mb, 0, (size_t)NC * DSP * 4, stream);
  hipMemsetAsync(vb, 0, (size_t)NC * DSP * 4, stream);
  k_setup_q<<<256, 256, 0, stream>>>(query_in, q0, Qh, Ql, Qth, Qtl);
  k_setup_p<<<128, 256, 0, stream>>>(protos_in, p0, Ps, Ph, Pl);

  for (int it = 1; it <= NITER; ++it) {
    float bc1 = 1.0f - powf(0.9f, (float)it);
    float bc2 = 1.0f - powf(0.999f, (float)it);
    k_gemm1<<<1024, 256, 0, stream>>>(Qh, Ql, Ph, Pl, q0, p0, S);
    k_rowstats<<<NPART, 256, 0, stream>>>(S, rowZ, colp);
    k_colfin<<<64, 256, 0, stream>>>(colp, Avec);
    k_gwrite<<<256, 1024, 0, stream>>>(S, rowZ, Avec, Gth, Gtl);
    k_gemm2<<<512, 256, 0, stream>>>(Gth, Gtl, Qth, Qtl, gradp);
    k_adam<<<NC, 256, 0, stream>>>(gradp, Ps, mb, vb, p0, Ph, Pl, bc1, bc2);
  }
  k_out<<<512, 256, 0, stream>>>(p0, Ps, (float*)d_out);
}